// Round 3
// baseline (26279.544 us; speedup 1.0000x reference)
//
#include <hip/hip_runtime.h>
#include <cmath>

#define NB    256   // batch
#define NT    64    // time points
#define DATA  256
#define DD    264   // DATA + AUG
#define WID   256   // MLP width
#define NSUB  4
#define NTH   1024  // threads per block (16 waves)
#define NW    16    // waves per block
#define PSS   264   // partial-sum row stride (floats)

// Transposed-weight offsets in d_ws (floats). WT_l[k][j] = W_l[j][k].
#define OFF_WT0 0
#define OFF_WT1 (DD * WID)              // 67584
#define OFF_WT2 (OFF_WT1 + WID * WID)   // 133120
#define OFF_WT3 (OFF_WT2 + WID * WID)   // 198656

__global__ void transpose_weights(const float* __restrict__ W0,
                                  const float* __restrict__ W1,
                                  const float* __restrict__ W2,
                                  const float* __restrict__ W3,
                                  float* __restrict__ ws) {
  const int stride = gridDim.x * blockDim.x;
  const int tid = blockIdx.x * blockDim.x + threadIdx.x;
  // WT0[k][j] = W0[j][k]   (k<DD, j<WID)
  for (int i = tid; i < DD * WID; i += stride) {
    int k = i >> 8, j = i & 255;
    ws[OFF_WT0 + i] = W0[j * DD + k];
  }
  // WT1/WT2: [k][j] = W[j][k]  (k<WID, j<WID)
  for (int i = tid; i < WID * WID; i += stride) {
    int k = i >> 8, j = i & 255;
    ws[OFF_WT1 + i] = W1[j * WID + k];
  }
  for (int i = tid; i < WID * WID; i += stride) {
    int k = i >> 8, j = i & 255;
    ws[OFF_WT2 + i] = W2[j * WID + k];
  }
  // WT3[k][j] = W3[j][k]   (k<WID, j<DD)
  for (int i = tid; i < WID * DD; i += stride) {
    int k = i / DD, j = i - k * DD;
    ws[OFF_WT3 + i] = W3[j * WID + k];
  }
}

struct P4 {
  const float *WT0, *WT1, *WT2, *WT3;
  const float *b0, *b1, *b2, *b3;
};

// One layer: fout[N] = act(W[N,K] @ fin[K] + b), using WT[K][N] (K-major).
// Wave w handles k in {w, w+16, ...}; lane l accumulates rows 4l..4l+3 in
// registers (coalesced 1KB global read per k). 16-way partial reduce via LDS.
// EXTRA: N==264 -> lanes 0..7 also accumulate rows 256..263 (scalar reads).
template <int K, int N, bool DO_TANH, bool EXTRA>
__device__ __forceinline__ void layerT(const float* __restrict__ WT,
                                       const float* __restrict__ bias,
                                       const float* __restrict__ fin,
                                       float* __restrict__ fout,
                                       float* __restrict__ ps,
                                       int wave, int lane, int tid) {
  constexpr int N4 = N / 4;   // 64 or 66
  const float4* __restrict__ WT4 = reinterpret_cast<const float4*>(WT);
  float4 acc; acc.x = acc.y = acc.z = acc.w = 0.f;
  float accx = 0.f;
#pragma unroll
  for (int i = 0; i < 16; ++i) {
    const int k = wave + i * NW;            // < 256 always
    const float fk = fin[k];                // LDS broadcast (wave-uniform addr)
    const float4 wv = WT4[k * N4 + lane];   // coalesced: 64 lanes = 1KB line
    acc.x = fmaf(fk, wv.x, acc.x);
    acc.y = fmaf(fk, wv.y, acc.y);
    acc.z = fmaf(fk, wv.z, acc.z);
    acc.w = fmaf(fk, wv.w, acc.w);
    if (EXTRA) {
      if (lane < 8) accx = fmaf(fk, WT[k * N + 256 + lane], accx);
    }
  }
  if (K == DD) {                            // tail k = 256..263 (layer 0 only)
    if (wave < 8) {
      const int k = 256 + wave;
      const float fk = fin[k];
      const float4 wv = WT4[k * N4 + lane];
      acc.x = fmaf(fk, wv.x, acc.x);
      acc.y = fmaf(fk, wv.y, acc.y);
      acc.z = fmaf(fk, wv.z, acc.z);
      acc.w = fmaf(fk, wv.w, acc.w);
    }
  }
  // partial sums: ps[wave][4*lane .. 4*lane+3], conflict-free b128 writes
  float4* psw = reinterpret_cast<float4*>(ps + wave * PSS);
  psw[lane] = acc;
  if (EXTRA) {
    if (lane < 8) ps[wave * PSS + 256 + lane] = accx;
  }
  __syncthreads();
  if (tid < N) {
    float s = bias[tid];
#pragma unroll
    for (int w = 0; w < NW; ++w) s += ps[w * PSS + tid];  // lanes consecutive -> conflict-free
    fout[tid] = DO_TANH ? tanhf(s) : s;
  }
  __syncthreads();
}

__device__ __forceinline__ void f_eval(const P4& P,
                                       const float* __restrict__ fin,
                                       float* __restrict__ fout,
                                       float* __restrict__ h1,
                                       float* __restrict__ h2,
                                       float* __restrict__ ps,
                                       int wave, int lane, int tid) {
  layerT<DD,  WID, true,  false>(P.WT0, P.b0, fin, h1,  ps, wave, lane, tid);
  layerT<WID, WID, true,  false>(P.WT1, P.b1, h1,  h2,  ps, wave, lane, tid);
  layerT<WID, WID, true,  false>(P.WT2, P.b2, h2,  h1,  ps, wave, lane, tid);
  layerT<WID, DD,  false, true >(P.WT3, P.b3, h1,  fout, ps, wave, lane, tid);
}

__global__ __launch_bounds__(NTH) void node_integrate(
    const float* __restrict__ ts, const float* __restrict__ xs,
    const float* __restrict__ a_sample, P4 P,
    float* __restrict__ out) {
  const int b    = blockIdx.x;
  const int tid  = threadIdx.x;
  const int wave = tid >> 6;
  const int lane = tid & 63;

  __shared__ __align__(16) float s_y[DD];
  __shared__ __align__(16) float s_in[DD];
  __shared__ __align__(16) float s_k[DD];
  __shared__ __align__(16) float s_acc[DD];
  __shared__ __align__(16) float s_h1[WID];
  __shared__ __align__(16) float s_h2[WID];
  __shared__ __align__(16) float s_ps[NW * PSS];

  // y0 = concat(a * exp(-0.1*t0) * sin(pi*x), zeros(AUG))
  if (tid < DD) {
    float v = 0.f;
    if (tid < DATA) {
      float x = xs[(size_t)b * DATA + tid];
      float scale = a_sample[b] * expf(-0.1f * ts[0]);
      v = scale * sinf(3.14159265358979323846f * x);
    }
    s_y[tid] = v;
  }
  __syncthreads();

  if (tid < DATA) out[((size_t)b * NT + 0) * DATA + tid] = s_y[tid];

  for (int t = 0; t < NT - 1; ++t) {
    const float dt = ts[t + 1] - ts[t];
    const float h  = dt * (1.0f / NSUB);
    for (int sub = 0; sub < NSUB; ++sub) {
      // k1
      f_eval(P, s_y, s_k, s_h1, s_h2, s_ps, wave, lane, tid);
      if (tid < DD) {
        float k1 = s_k[tid];
        s_acc[tid] = (2.0f / 9.0f) * k1;
        s_in[tid]  = s_y[tid] + 0.5f * h * k1;
      }
      __syncthreads();
      // k2
      f_eval(P, s_in, s_k, s_h1, s_h2, s_ps, wave, lane, tid);
      if (tid < DD) {
        float k2 = s_k[tid];
        s_acc[tid] += (1.0f / 3.0f) * k2;
        s_in[tid] = s_y[tid] + 0.75f * h * k2;
      }
      __syncthreads();
      // k3 + combine
      f_eval(P, s_in, s_k, s_h1, s_h2, s_ps, wave, lane, tid);
      if (tid < DD) {
        float k3 = s_k[tid];
        s_y[tid] += h * (s_acc[tid] + (4.0f / 9.0f) * k3);
      }
      __syncthreads();
    }
    if (tid < DATA) out[((size_t)b * NT + (t + 1)) * DATA + tid] = s_y[tid];
  }
}

extern "C" void kernel_launch(void* const* d_in, const int* in_sizes, int n_in,
                              void* d_out, int out_size, void* d_ws, size_t ws_size,
                              hipStream_t stream) {
  const float* ts = (const float*)d_in[0];
  const float* xs = (const float*)d_in[1];
  const float* a  = (const float*)d_in[2];
  const float* W0 = (const float*)d_in[3];
  const float* b0 = (const float*)d_in[4];
  const float* W1 = (const float*)d_in[5];
  const float* b1 = (const float*)d_in[6];
  const float* W2 = (const float*)d_in[7];
  const float* b2 = (const float*)d_in[8];
  const float* W3 = (const float*)d_in[9];
  const float* b3 = (const float*)d_in[10];
  float* ws = (float*)d_ws;
  float* out = (float*)d_out;

  hipLaunchKernelGGL(transpose_weights, dim3(256), dim3(256), 0, stream,
                     W0, W1, W2, W3, ws);

  P4 P;
  P.WT0 = ws + OFF_WT0;
  P.WT1 = ws + OFF_WT1;
  P.WT2 = ws + OFF_WT2;
  P.WT3 = ws + OFF_WT3;
  P.b0 = b0; P.b1 = b1; P.b2 = b2; P.b3 = b3;

  hipLaunchKernelGGL(node_integrate, dim3(NB), dim3(NTH), 0, stream,
                     ts, xs, a, P, out);
}